// Round 1
// baseline (1204.399 us; speedup 1.0000x reference)
//
#include <hip/hip_runtime.h>
#include <math.h>

#define H_ 128
static constexpr int NG_ = 20000, NP_ = 3000, B_ = 2;
static constexpr int EGG_ = 200000, ETG_ = 200000, EGP_ = 200000, EPP_ = 100000;
static constexpr float TAU_ = 0.5f;
static constexpr float RSQRTH_ = 0.088388347648318447f; // 1/sqrt(128)

// ---------------- CSR build ----------------
__global__ void hist_k(const int* __restrict__ d, int* __restrict__ c, int E) {
  int i = blockIdx.x * 256 + threadIdx.x;
  if (i < E) atomicAdd(&c[d[i]], 1);
}

__global__ void exscan_k(const int* __restrict__ cnt, int* __restrict__ off, int n) {
  __shared__ int sh[256];
  const int tid = threadIdx.x;
  if (tid == 0) off[0] = 0;
  int run = 0;
  for (int base = 0; base < n; base += 4096) {
    int loc[16];
    int s = 0;
#pragma unroll
    for (int j = 0; j < 16; ++j) {
      int i = base + tid * 16 + j;
      loc[j] = (i < n) ? cnt[i] : 0;
      s += loc[j];
    }
    sh[tid] = s;
    __syncthreads();
    for (int st = 1; st < 256; st <<= 1) {
      int v = (tid >= st) ? sh[tid - st] : 0;
      __syncthreads();
      sh[tid] += v;
      __syncthreads();
    }
    int acc = run + ((tid > 0) ? sh[tid - 1] : 0);
    int tot = sh[255];
    __syncthreads();  // protect sh before next iteration's writes
#pragma unroll
    for (int j = 0; j < 16; ++j) {
      int i = base + tid * 16 + j;
      acc += loc[j];
      if (i < n) off[i + 1] = acc;
    }
    run += tot;
  }
}

__global__ void scatter_k(const int* __restrict__ d, const int* __restrict__ off,
                          int* __restrict__ cur, int* __restrict__ bkt, int E) {
  int i = blockIdx.x * 256 + threadIdx.x;
  if (i < E) {
    int t = d[i];
    int p = atomicAdd(&cur[t], 1);
    bkt[off[t] + p] = i;
  }
}

// ---------------- GEMM: Y[R,128] = (ACCUM?Y:0) + act(X[R,128] @ W[128,128] + bias) ----------------
// 256 threads, 64-row tile. W fully staged in LDS; A-tile staged transposed.
template <int RELU, int ACCUM>
__global__ __launch_bounds__(256, 2) void gemm128_k(const float* __restrict__ X,
                                                    const float* __restrict__ W,
                                                    const float* __restrict__ bias,
                                                    float* __restrict__ Y, int R) {
  __shared__ float Wl[128 * 128];
  __shared__ float Al[32][68];
  const int t = threadIdx.x;
  const int tx = t & 31, ty = t >> 5;
  const int r0 = blockIdx.x * 64;
  {
    const float4* Wv = (const float4*)W;
    float4* Wlv = (float4*)Wl;
#pragma unroll
    for (int i = 0; i < 16; ++i) Wlv[t + 256 * i] = Wv[t + 256 * i];
  }
  float acc[8][4];
#pragma unroll
  for (int i = 0; i < 8; ++i)
#pragma unroll
    for (int j = 0; j < 4; ++j) acc[i][j] = 0.f;

  for (int kc = 0; kc < 128; kc += 32) {
    __syncthreads();
#pragma unroll
    for (int it = 0; it < 2; ++it) {
      int idx = t + 256 * it;  // 0..511
      int row = idx >> 3;      // 0..63
      int kq = idx & 7;        // k = kq*4
      int gr = r0 + row;
      float4 v = (gr < R) ? *(const float4*)&X[(size_t)gr * 128 + kc + kq * 4]
                          : make_float4(0.f, 0.f, 0.f, 0.f);
      Al[kq * 4 + 0][row] = v.x;
      Al[kq * 4 + 1][row] = v.y;
      Al[kq * 4 + 2][row] = v.z;
      Al[kq * 4 + 3][row] = v.w;
    }
    __syncthreads();
#pragma unroll
    for (int k = 0; k < 32; ++k) {
      float4 a0 = *(const float4*)&Al[k][ty * 8];
      float4 a1 = *(const float4*)&Al[k][ty * 8 + 4];
      float4 w = *(const float4*)&Wl[(kc + k) * 128 + tx * 4];
      float a[8] = {a0.x, a0.y, a0.z, a0.w, a1.x, a1.y, a1.z, a1.w};
#pragma unroll
      for (int i = 0; i < 8; ++i) {
        acc[i][0] += a[i] * w.x;
        acc[i][1] += a[i] * w.y;
        acc[i][2] += a[i] * w.z;
        acc[i][3] += a[i] * w.w;
      }
    }
  }
  float4 bv = make_float4(0.f, 0.f, 0.f, 0.f);
  if (bias) bv = *(const float4*)&bias[tx * 4];
#pragma unroll
  for (int i = 0; i < 8; ++i) {
    int gr = r0 + ty * 8 + i;
    if (gr < R) {
      float4 o;
      o.x = acc[i][0] + bv.x;
      o.y = acc[i][1] + bv.y;
      o.z = acc[i][2] + bv.z;
      o.w = acc[i][3] + bv.w;
      if (RELU) {
        o.x = fmaxf(o.x, 0.f); o.y = fmaxf(o.y, 0.f);
        o.z = fmaxf(o.z, 0.f); o.w = fmaxf(o.w, 0.f);
      }
      float4* yp = (float4*)&Y[(size_t)gr * 128 + tx * 4];
      if (ACCUM) {
        float4 old = *yp;
        o.x += old.x; o.y += old.y; o.z += old.z; o.w += old.w;
      }
      *yp = o;
    }
  }
}

// ---------------- per-edge attention scores ----------------
// one wave per edge: s = sigmoid(dot(Q[dst], K[src]) / sqrt(H) * ew[e])
__global__ void edge_score_k(const float* __restrict__ Q, const float* __restrict__ K,
                             const int* __restrict__ dst, const int* __restrict__ src,
                             const float* __restrict__ ew, float* __restrict__ S, int E,
                             int nQ, int nK) {
  int lane = threadIdx.x & 63;
  int e = blockIdx.x * 4 + (threadIdx.x >> 6);
  int b = blockIdx.y;
  if (e >= E) return;
  int de = dst[e], se = src[e];
  const float2 q = *(const float2*)&Q[((size_t)b * nQ + de) * 128 + lane * 2];
  const float2 k = *(const float2*)&K[((size_t)b * nK + se) * 128 + lane * 2];
  float p = q.x * k.x + q.y * k.y;
#pragma unroll
  for (int s_ = 32; s_; s_ >>= 1) p += __shfl_xor(p, s_);
  if (lane == 0) {
    float raw = p * RSQRTH_ * ew[e];
    S[(size_t)b * E + e] = 1.f / (1.f + expf(-raw));
  }
}

// ---------------- aggregation (optionally with per-target top-k pruning) ----------------
// block = 128 threads = one (batch, target). out[b,t,:] += sum_i w_i * V[b, fidx[e_i], :]
template <int PRUNE>
__global__ __launch_bounds__(128) void agg_k(const int* __restrict__ off,
                                             const int* __restrict__ bkt,
                                             const int* __restrict__ fidx,
                                             const float* __restrict__ ew,
                                             const float* __restrict__ S, int Etot, int topk,
                                             const float* __restrict__ V, int nV,
                                             float* __restrict__ out, int nT) {
  __shared__ float s_sh[1024];
  __shared__ int e_sh[1024];
  __shared__ int f_sh[1024];
  const int t = blockIdx.x, b = blockIdx.y;
  const int tid = threadIdx.x;
  const int o0 = off[t];
  int ne = off[t + 1] - o0;
  ne = min(ne, 1024);
  for (int i = tid; i < ne; i += 128) {
    int e = bkt[o0 + i];
    f_sh[i] = fidx[e];
    if (PRUNE) {
      e_sh[i] = e;
      s_sh[i] = S[(size_t)b * Etot + e];
    } else {
      s_sh[i] = ew[e];
    }
  }
  __syncthreads();
  if (PRUNE) {
    float nsel[8];
    int ii = 0;
    for (int i = tid; i < ne; i += 128, ++ii) {
      float si = s_sh[i];
      int ei = e_sh[i];
      int cnt = 0;
      for (int j = 0; j < ne; ++j) {
        float sj = s_sh[j];
        cnt += (sj > si) || (sj == si && e_sh[j] < ei);
      }
      nsel[ii] = ((cnt < topk) && (si > TAU_)) ? si : 0.f;
    }
    __syncthreads();
    ii = 0;
    for (int i = tid; i < ne; i += 128, ++ii) s_sh[i] = nsel[ii];
    __syncthreads();
  }
  size_t oidx = ((size_t)b * nT + t) * 128 + tid;
  float acc = out[oidx];
  for (int i = 0; i < ne; ++i) {
    float w = s_sh[i];
    if (w != 0.f) acc += w * V[((size_t)b * nV + f_sh[i]) * 128 + tid];
  }
  out[oidx] = acc;
}

// ---------------- host ----------------
extern "C" void kernel_launch(void* const* d_in, const int* in_sizes, int n_in, void* d_out,
                              int out_size, void* d_ws, size_t ws_size, hipStream_t stream) {
  const float* gene = (const float*)d_in[0];
  const float* path = (const float*)d_in[1];
  const float* gg_w = (const float*)d_in[2];
  const float* tg_w = (const float*)d_in[3];
  const float* gp_w = (const float*)d_in[4];
  const float* pp_w = (const float*)d_in[5];
  const int* gg_src = (const int*)d_in[6];
  const int* gg_dst = (const int*)d_in[7];
  const int* tg_src = (const int*)d_in[8];
  const int* tg_dst = (const int*)d_in[9];
  const int* gp_src = (const int*)d_in[10];
  const int* gp_dst = (const int*)d_in[11];
  const int* pp_src = (const int*)d_in[12];
  const int* pp_dst = (const int*)d_in[13];
  const float* mgg_w1 = (const float*)d_in[14];
  const float* mgg_b1 = (const float*)d_in[15];
  const float* mgg_w2 = (const float*)d_in[16];
  const float* mgg_b2 = (const float*)d_in[17];
  const float* mgp_w1 = (const float*)d_in[18];
  const float* mgp_b1 = (const float*)d_in[19];
  const float* mgp_w2 = (const float*)d_in[20];
  const float* mgp_b2 = (const float*)d_in[21];
  const float* mpp_w1 = (const float*)d_in[22];
  const float* mpp_b1 = (const float*)d_in[23];
  const float* mpp_w2 = (const float*)d_in[24];
  const float* mpp_b2 = (const float*)d_in[25];
  const float* mpg_w1 = (const float*)d_in[26];
  const float* mpg_b1 = (const float*)d_in[27];
  const float* mpg_w2 = (const float*)d_in[28];
  const float* mpg_b2 = (const float*)d_in[29];
  const float* w_gg = (const float*)d_in[30];
  const float* w_pp = (const float*)d_in[31];
  const float* w_pg = (const float*)d_in[32];
  const float* tg_q = (const float*)d_in[33];
  const float* tg_k = (const float*)d_in[34];
  const float* tg_v_tf = (const float*)d_in[35];
  const float* tg_v_gene = (const float*)d_in[36];
  const float* gp_q = (const float*)d_in[37];
  const float* gp_k = (const float*)d_in[38];
  const float* gp_v = (const float*)d_in[39];

  float* out_final = (float*)d_out;                               // [B,NG,H]
  float* out_h3 = (float*)d_out + (size_t)B_ * NG_ * H_;          // [B,NP,H]

  const size_t BNGH = (size_t)B_ * NG_ * H_;  // 5.12M floats
  const size_t BNPH = (size_t)B_ * NP_ * H_;  // 0.768M floats

  char* wp = (char*)d_ws;
  auto alloc = [&](size_t bytes) {
    void* p = (void*)wp;
    wp += (bytes + 255) & ~(size_t)255;
    return p;
  };
  float* G0 = (float*)alloc(BNGH * 4);  // h1
  float* G1 = (float*)alloc(BNGH * 4);  // mlp hidden (gene-sized)
  float* G2 = (float*)alloc(BNGH * 4);  // Xw / q_gene / k_g
  float* G3 = (float*)alloc(BNGH * 4);  // k_tf / v_g
  float* G4 = (float*)alloc(BNGH * 4);  // v_tf
  float* G5 = (float*)alloc(BNGH * 4);  // h2 (v_gene + agg)
  float* P0 = (float*)alloc(BNPH * 4);  // q_p / Yw / Zw
  float* P1 = (float*)alloc(BNPH * 4);  // pathway mlp hidden
  float* P2 = (float*)alloc(BNPH * 4);  // bar_h3
  float* Stg = (float*)alloc((size_t)B_ * ETG_ * 4);
  float* Sgp = (float*)alloc((size_t)B_ * EGP_ * 4);
  int* cnt = (int*)alloc((size_t)NG_ * 4);
  int* off_gg = (int*)alloc((size_t)(NG_ + 1) * 4);
  int* off_tg = (int*)alloc((size_t)(NG_ + 1) * 4);
  int* off_gpd = (int*)alloc((size_t)(NP_ + 1) * 4);
  int* off_pp = (int*)alloc((size_t)(NP_ + 1) * 4);
  int* off_gps = (int*)alloc((size_t)(NG_ + 1) * 4);
  int* bkt_gg = (int*)alloc((size_t)EGG_ * 4);
  int* bkt_tg = (int*)alloc((size_t)ETG_ * 4);
  int* bkt_gpd = (int*)alloc((size_t)EGP_ * 4);
  int* bkt_pp = (int*)alloc((size_t)EPP_ * 4);
  int* bkt_gps = (int*)alloc((size_t)EGP_ * 4);

  auto build_csr = [&](const int* dstArr, int E, int N, int* off, int* bkt) {
    hipMemsetAsync(cnt, 0, (size_t)N * 4, stream);
    hist_k<<<dim3((E + 255) / 256), dim3(256), 0, stream>>>(dstArr, cnt, E);
    exscan_k<<<dim3(1), dim3(256), 0, stream>>>(cnt, off, N);
    hipMemsetAsync(cnt, 0, (size_t)N * 4, stream);
    scatter_k<<<dim3((E + 255) / 256), dim3(256), 0, stream>>>(dstArr, off, cnt, bkt, E);
  };
  build_csr(gg_dst, EGG_, NG_, off_gg, bkt_gg);
  build_csr(tg_dst, ETG_, NG_, off_tg, bkt_tg);
  build_csr(gp_dst, EGP_, NP_, off_gpd, bkt_gpd);
  build_csr(pp_dst, EPP_, NP_, off_pp, bkt_pp);
  build_csr(gp_src, EGP_, NG_, off_gps, bkt_gps);

  const int RG = B_ * NG_;  // 40000
  const int RP = B_ * NP_;  // 6000
  auto gemm = [&](const float* X, const float* W, const float* bias, float* Y, int R, bool relu,
                  bool accum) {
    dim3 g((R + 63) / 64), blk(256);
    if (relu)
      gemm128_k<1, 0><<<g, blk, 0, stream>>>(X, W, bias, Y, R);
    else if (accum)
      gemm128_k<0, 1><<<g, blk, 0, stream>>>(X, W, bias, Y, R);
    else
      gemm128_k<0, 0><<<g, blk, 0, stream>>>(X, W, bias, Y, R);
  };

  // ---- Layer 1: h1 = mlp_gg(gene) + scatter(gg_w * (gene@w_gg)[src]) ----
  gemm(gene, w_gg, nullptr, G2, RG, false, false);       // Xw
  gemm(gene, mgg_w1, mgg_b1, G1, RG, true, false);       // hidden
  gemm(G1, mgg_w2, mgg_b2, G0, RG, false, false);        // h1 base
  agg_k<0><<<dim3(NG_, B_), dim3(128), 0, stream>>>(off_gg, bkt_gg, gg_src, gg_w, nullptr, 0, 0,
                                                    G2, NG_, G0, NG_);
  // ---- Layer 2: TF->gene attention ----
  gemm(G0, tg_q, nullptr, G2, RG, false, false);         // q_gene
  gemm(G0, tg_k, nullptr, G3, RG, false, false);         // k_tf
  gemm(G0, tg_v_tf, nullptr, G4, RG, false, false);      // v_tf
  gemm(G0, tg_v_gene, nullptr, G5, RG, false, false);    // v_gene -> h2 base
  edge_score_k<<<dim3((ETG_ + 3) / 4, B_), dim3(256), 0, stream>>>(G2, G3, tg_dst, tg_src, tg_w,
                                                                   Stg, ETG_, NG_, NG_);
  agg_k<1><<<dim3(NG_, B_), dim3(128), 0, stream>>>(off_tg, bkt_tg, tg_src, nullptr, Stg, ETG_,
                                                    16, G4, NG_, G5, NG_);  // h2
  // ---- Layer 3: gene->pathway attention ----
  gemm(G5, gp_k, nullptr, G2, RG, false, false);         // k_g
  gemm(G5, gp_v, nullptr, G3, RG, false, false);         // v_g
  gemm(path, gp_q, nullptr, P0, RP, false, false);       // q_p
  edge_score_k<<<dim3((EGP_ + 3) / 4, B_), dim3(256), 0, stream>>>(P0, G2, gp_dst, gp_src, gp_w,
                                                                   Sgp, EGP_, NP_, NG_);
  gemm(path, mgp_w1, mgp_b1, P1, RP, true, false);
  gemm(P1, mgp_w2, mgp_b2, P2, RP, false, false);        // bar base
  agg_k<1><<<dim3(NP_, B_), dim3(128), 0, stream>>>(off_gpd, bkt_gpd, gp_src, nullptr, Sgp, EGP_,
                                                    32, G3, NG_, P2, NP_);  // bar_h3
  // ---- Layer 4: pathway-pathway ----
  gemm(P2, w_pp, nullptr, P0, RP, false, false);         // Yw
  gemm(P2, mpp_w1, mpp_b1, P1, RP, true, false);
  gemm(P1, mpp_w2, mpp_b2, out_h3, RP, false, false);    // h3 base
  agg_k<0><<<dim3(NP_, B_), dim3(128), 0, stream>>>(off_pp, bkt_pp, pp_src, pp_w, nullptr, 0, 0,
                                                    P0, NP_, out_h3, NP_);  // h3
  // ---- Layer 5: pathway->gene feedback ----
  gemm(out_h3, w_pg, nullptr, P0, RP, false, false);     // Zw
  gemm(G5, mpg_w1, mpg_b1, G1, RG, true, false);
  gemm(G1, mpg_w2, mpg_b2, out_final, RG, false, false); // final base
  agg_k<0><<<dim3(NG_, B_), dim3(128), 0, stream>>>(off_gps, bkt_gps, gp_dst, gp_w, nullptr, 0, 0,
                                                    P0, NP_, out_final, NG_);
  (void)in_sizes; (void)n_in; (void)out_size; (void)ws_size;
}

// Round 3
// 889.811 us; speedup vs baseline: 1.3535x; 1.3535x over previous
//
#include <hip/hip_runtime.h>
#include <math.h>

#define H_ 128
static constexpr int NG_ = 20000, NP_ = 3000, B_ = 2;
static constexpr int EGG_ = 200000, ETG_ = 200000, EGP_ = 200000, EPP_ = 100000;
static constexpr float TAU_ = 0.5f;
static constexpr float RSQRTH_ = 0.088388347648318447f; // 1/sqrt(128)

// ---------------- batched CSR build ----------------
struct CsrDesc {
  const int* dst;
  int E, N;
  int* cnt;
  int* cur;
  int* off;
  int* bkt;
};
struct CsrPack { CsrDesc c[5]; };

__global__ void hist_all_k(CsrPack p) {
  CsrDesc d = p.c[blockIdx.y];
  int i = blockIdx.x * 256 + threadIdx.x;
  if (i < d.E) atomicAdd(&d.cnt[d.dst[i]], 1);
}

__global__ void scatter_all_k(CsrPack p) {
  CsrDesc d = p.c[blockIdx.y];
  int i = blockIdx.x * 256 + threadIdx.x;
  if (i < d.E) {
    int t = d.dst[i];
    int pos = atomicAdd(&d.cur[t], 1);
    d.bkt[d.off[t] + pos] = i;
  }
}

__global__ void exscan_all_k(CsrPack p) {
  CsrDesc d = p.c[blockIdx.x];
  const int n = d.N;
  const int* cnt = d.cnt;
  int* off = d.off;
  __shared__ int sh[256];
  const int tid = threadIdx.x;
  if (tid == 0) off[0] = 0;
  int run = 0;
  for (int base = 0; base < n; base += 4096) {
    int loc[16];
    int s = 0;
#pragma unroll
    for (int j = 0; j < 16; ++j) {
      int i = base + tid * 16 + j;
      loc[j] = (i < n) ? cnt[i] : 0;
      s += loc[j];
    }
    sh[tid] = s;
    __syncthreads();
    for (int st = 1; st < 256; st <<= 1) {
      int v = (tid >= st) ? sh[tid - st] : 0;
      __syncthreads();
      sh[tid] += v;
      __syncthreads();
    }
    int acc = run + ((tid > 0) ? sh[tid - 1] : 0);
    int tot = sh[255];
    __syncthreads();
#pragma unroll
    for (int j = 0; j < 16; ++j) {
      int i = base + tid * 16 + j;
      acc += loc[j];
      if (i < n) off[i + 1] = acc;
    }
    run += tot;
  }
}

// ---------------- GEMM: Y[R,128] = act(X[R,128] @ W[128,128] + bias) ----------------
template <int RELU, int ACCUM>
__global__ __launch_bounds__(256, 2) void gemm128_k(const float* __restrict__ X,
                                                    const float* __restrict__ W,
                                                    const float* __restrict__ bias,
                                                    float* __restrict__ Y, int R) {
  __shared__ float Wl[128 * 128];
  __shared__ float Al[32][68];
  const int t = threadIdx.x;
  const int tx = t & 31, ty = t >> 5;
  const int r0 = blockIdx.x * 64;
  {
    const float4* Wv = (const float4*)W;
    float4* Wlv = (float4*)Wl;
#pragma unroll
    for (int i = 0; i < 16; ++i) Wlv[t + 256 * i] = Wv[t + 256 * i];
  }
  float acc[8][4];
#pragma unroll
  for (int i = 0; i < 8; ++i)
#pragma unroll
    for (int j = 0; j < 4; ++j) acc[i][j] = 0.f;

  for (int kc = 0; kc < 128; kc += 32) {
    __syncthreads();
#pragma unroll
    for (int it = 0; it < 2; ++it) {
      int idx = t + 256 * it;
      int row = idx >> 3;
      int kq = idx & 7;
      int gr = r0 + row;
      float4 v = (gr < R) ? *(const float4*)&X[(size_t)gr * 128 + kc + kq * 4]
                          : make_float4(0.f, 0.f, 0.f, 0.f);
      Al[kq * 4 + 0][row] = v.x;
      Al[kq * 4 + 1][row] = v.y;
      Al[kq * 4 + 2][row] = v.z;
      Al[kq * 4 + 3][row] = v.w;
    }
    __syncthreads();
#pragma unroll
    for (int k = 0; k < 32; ++k) {
      float4 a0 = *(const float4*)&Al[k][ty * 8];
      float4 a1 = *(const float4*)&Al[k][ty * 8 + 4];
      float4 w = *(const float4*)&Wl[(kc + k) * 128 + tx * 4];
      float a[8] = {a0.x, a0.y, a0.z, a0.w, a1.x, a1.y, a1.z, a1.w};
#pragma unroll
      for (int i = 0; i < 8; ++i) {
        acc[i][0] += a[i] * w.x;
        acc[i][1] += a[i] * w.y;
        acc[i][2] += a[i] * w.z;
        acc[i][3] += a[i] * w.w;
      }
    }
  }
  float4 bv = make_float4(0.f, 0.f, 0.f, 0.f);
  if (bias) bv = *(const float4*)&bias[tx * 4];
#pragma unroll
  for (int i = 0; i < 8; ++i) {
    int gr = r0 + ty * 8 + i;
    if (gr < R) {
      float4 o;
      o.x = acc[i][0] + bv.x;
      o.y = acc[i][1] + bv.y;
      o.z = acc[i][2] + bv.z;
      o.w = acc[i][3] + bv.w;
      if (RELU) {
        o.x = fmaxf(o.x, 0.f); o.y = fmaxf(o.y, 0.f);
        o.z = fmaxf(o.z, 0.f); o.w = fmaxf(o.w, 0.f);
      }
      float4* yp = (float4*)&Y[(size_t)gr * 128 + tx * 4];
      if (ACCUM) {
        float4 old = *yp;
        o.x += old.x; o.y += old.y; o.z += old.z; o.w += old.w;
      }
      *yp = o;
    }
  }
}

// ---------------- fused attention: score + top-k prune + aggregate ----------------
// 256 threads = 4 waves; each wave owns one (batch,target). All LDS strictly
// per-wave slices -> no __syncthreads needed (wave lockstep orders phases).
__global__ __launch_bounds__(256) void attn_agg_k(
    const int* __restrict__ off, const int* __restrict__ bkt,
    const int* __restrict__ fidx, const float* __restrict__ ew,
    const float* __restrict__ Q, const float* __restrict__ K,
    const float* __restrict__ V, float* __restrict__ out,
    int nT, int nS, int topk) {
  constexpr int CAP = 512;
  __shared__ float s_sh[4][CAP];
  __shared__ int f_sh[4][CAP];
  __shared__ int e_sh[4][CAP];
  __shared__ float q_sh[4][128];
  const int wv = threadIdx.x >> 6, lane = threadIdx.x & 63;
  const int t = blockIdx.x * 4 + wv, b = blockIdx.y;
  if (t >= nT) return;
  const int o0 = off[t];
  const int ne = min(off[t + 1] - o0, CAP);
  if (ne == 0) return;

  // stage bucket: edge id, source node, edge weight (ew parked in s_sh)
  for (int i = lane; i < ne; i += 64) {
    int e = bkt[o0 + i];
    f_sh[wv][i] = fidx[e];
    e_sh[wv][i] = e;
    s_sh[wv][i] = ew[e];
  }
  // stage Q row (once per target, not once per edge)
  const float2 qv = *(const float2*)&Q[((size_t)b * nT + t) * 128 + lane * 2];
  *(float2*)&q_sh[wv][lane * 2] = qv;

  const int g = lane >> 4, l = lane & 15;  // 4 quarter-wave groups
  const float4 q0 = *(const float4*)&q_sh[wv][l * 4];
  const float4 q1 = *(const float4*)&q_sh[wv][64 + l * 4];

  // scores: 4 edges per iteration, one per quarter-wave
  for (int i0 = 0; i0 < ne; i0 += 4) {
    int idx = i0 + g;
    bool val = idx < ne;
    int f = f_sh[wv][val ? idx : (ne - 1)];
    const float4* kr = (const float4*)&K[((size_t)b * nS + f) * 128];
    float4 k0 = kr[l];
    float4 k1 = kr[16 + l];
    float p = k0.x * q0.x + k0.y * q0.y + k0.z * q0.z + k0.w * q0.w +
              k1.x * q1.x + k1.y * q1.y + k1.z * q1.z + k1.w * q1.w;
    p += __shfl_xor(p, 1);
    p += __shfl_xor(p, 2);
    p += __shfl_xor(p, 4);
    p += __shfl_xor(p, 8);
    if (l == 0 && val) {
      float w = s_sh[wv][idx];  // edge weight (read before overwrite)
      float raw = p * RSQRTH_ * w;
      s_sh[wv][idx] = 1.f / (1.f + expf(-raw));
    }
  }

  // prune: rank via pairwise count (stable: score desc, edge id asc)
  float keep[CAP / 64];
#pragma unroll
  for (int c = 0; c < CAP / 64; ++c) {
    int i = lane + c * 64;
    float r = 0.f;
    if (i < ne) {
      float si = s_sh[wv][i];
      int ei = e_sh[wv][i];
      int cnt = 0;
      for (int j = 0; j < ne; ++j) {
        float sj = s_sh[wv][j];
        cnt += (sj > si) || (sj == si && e_sh[wv][j] < ei);
      }
      r = (cnt < topk && si > TAU_) ? si : 0.f;
    }
    keep[c] = r;
  }
#pragma unroll
  for (int c = 0; c < CAP / 64; ++c) {
    int i = lane + c * 64;
    if (i < ne) s_sh[wv][i] = keep[c];
  }

  // aggregate: out[b,t,:] += sum_i s_i * V[b, f_i, :]
  size_t orow = ((size_t)b * nT + t) * 128 + lane * 2;
  float2 acc = *(float2*)&out[orow];
  for (int i = 0; i < ne; ++i) {
    float w = s_sh[wv][i];
    if (w != 0.f) {
      float2 v = *(const float2*)&V[((size_t)b * nS + f_sh[wv][i]) * 128 + lane * 2];
      acc.x += w * v.x;
      acc.y += w * v.y;
    }
  }
  *(float2*)&out[orow] = acc;
}

// ---------------- plain weighted aggregation (fixed edge weights) ----------------
__global__ __launch_bounds__(256) void wagg_k(
    const int* __restrict__ off, const int* __restrict__ bkt,
    const int* __restrict__ fidx, const float* __restrict__ ew,
    const float* __restrict__ V, float* __restrict__ out, int nT, int nS) {
  constexpr int CAP = 512;
  __shared__ float s_sh[4][CAP];
  __shared__ int f_sh[4][CAP];
  const int wv = threadIdx.x >> 6, lane = threadIdx.x & 63;
  const int t = blockIdx.x * 4 + wv, b = blockIdx.y;
  if (t >= nT) return;
  const int o0 = off[t];
  const int ne = min(off[t + 1] - o0, CAP);
  if (ne == 0) return;
  for (int i = lane; i < ne; i += 64) {
    int e = bkt[o0 + i];
    f_sh[wv][i] = fidx[e];
    s_sh[wv][i] = ew[e];
  }
  size_t orow = ((size_t)b * nT + t) * 128 + lane * 2;
  float2 acc = *(float2*)&out[orow];
  for (int i = 0; i < ne; ++i) {
    float w = s_sh[wv][i];
    float2 v = *(const float2*)&V[((size_t)b * nS + f_sh[wv][i]) * 128 + lane * 2];
    acc.x += w * v.x;
    acc.y += w * v.y;
  }
  *(float2*)&out[orow] = acc;
}

// ---------------- host ----------------
extern "C" void kernel_launch(void* const* d_in, const int* in_sizes, int n_in, void* d_out,
                              int out_size, void* d_ws, size_t ws_size, hipStream_t stream) {
  const float* gene = (const float*)d_in[0];
  const float* path = (const float*)d_in[1];
  const float* gg_w = (const float*)d_in[2];
  const float* tg_w = (const float*)d_in[3];
  const float* gp_w = (const float*)d_in[4];
  const float* pp_w = (const float*)d_in[5];
  const int* gg_src = (const int*)d_in[6];
  const int* gg_dst = (const int*)d_in[7];
  const int* tg_src = (const int*)d_in[8];
  const int* tg_dst = (const int*)d_in[9];
  const int* gp_src = (const int*)d_in[10];
  const int* gp_dst = (const int*)d_in[11];
  const int* pp_src = (const int*)d_in[12];
  const int* pp_dst = (const int*)d_in[13];
  const float* mgg_w1 = (const float*)d_in[14];
  const float* mgg_b1 = (const float*)d_in[15];
  const float* mgg_w2 = (const float*)d_in[16];
  const float* mgg_b2 = (const float*)d_in[17];
  const float* mgp_w1 = (const float*)d_in[18];
  const float* mgp_b1 = (const float*)d_in[19];
  const float* mgp_w2 = (const float*)d_in[20];
  const float* mgp_b2 = (const float*)d_in[21];
  const float* mpp_w1 = (const float*)d_in[22];
  const float* mpp_b1 = (const float*)d_in[23];
  const float* mpp_w2 = (const float*)d_in[24];
  const float* mpp_b2 = (const float*)d_in[25];
  const float* mpg_w1 = (const float*)d_in[26];
  const float* mpg_b1 = (const float*)d_in[27];
  const float* mpg_w2 = (const float*)d_in[28];
  const float* mpg_b2 = (const float*)d_in[29];
  const float* w_gg = (const float*)d_in[30];
  const float* w_pp = (const float*)d_in[31];
  const float* w_pg = (const float*)d_in[32];
  const float* tg_q = (const float*)d_in[33];
  const float* tg_k = (const float*)d_in[34];
  const float* tg_v_tf = (const float*)d_in[35];
  const float* tg_v_gene = (const float*)d_in[36];
  const float* gp_q = (const float*)d_in[37];
  const float* gp_k = (const float*)d_in[38];
  const float* gp_v = (const float*)d_in[39];

  float* out_final = (float*)d_out;                       // [B,NG,H]
  float* out_h3 = (float*)d_out + (size_t)B_ * NG_ * H_;  // [B,NP,H]

  const size_t BNGH = (size_t)B_ * NG_ * H_;
  const size_t BNPH = (size_t)B_ * NP_ * H_;

  char* wp = (char*)d_ws;
  auto alloc = [&](size_t bytes) {
    void* p = (void*)wp;
    wp += (bytes + 255) & ~(size_t)255;
    return p;
  };
  float* G0 = (float*)alloc(BNGH * 4);  // h1
  float* G1 = (float*)alloc(BNGH * 4);  // mlp hidden (gene-sized)
  float* G2 = (float*)alloc(BNGH * 4);  // Xw / q_gene / k_g
  float* G3 = (float*)alloc(BNGH * 4);  // k_tf / v_g
  float* G4 = (float*)alloc(BNGH * 4);  // v_tf
  float* G5 = (float*)alloc(BNGH * 4);  // h2
  float* P0 = (float*)alloc(BNPH * 4);  // q_p / Yw / Zw
  float* P1 = (float*)alloc(BNPH * 4);  // pathway mlp hidden
  float* P2 = (float*)alloc(BNPH * 4);  // bar_h3
  // CSR counters: cnt then cur, contiguous -> single memset
  const int NCNT = 3 * NG_ + 2 * NP_;  // gg, tg, gps (NG) + gpd, pp (NP)
  int* cntbuf = (int*)alloc((size_t)NCNT * 2 * 4);
  int* cnt_gg = cntbuf;
  int* cnt_tg = cnt_gg + NG_;
  int* cnt_gps = cnt_tg + NG_;
  int* cnt_gpd = cnt_gps + NG_;
  int* cnt_pp = cnt_gpd + NP_;
  int* cur0 = cntbuf + NCNT;
  int* cur_gg = cur0;
  int* cur_tg = cur_gg + NG_;
  int* cur_gps = cur_tg + NG_;
  int* cur_gpd = cur_gps + NG_;
  int* cur_pp = cur_gpd + NP_;
  int* off_gg = (int*)alloc((size_t)(NG_ + 1) * 4);
  int* off_tg = (int*)alloc((size_t)(NG_ + 1) * 4);
  int* off_gps = (int*)alloc((size_t)(NG_ + 1) * 4);
  int* off_gpd = (int*)alloc((size_t)(NP_ + 1) * 4);
  int* off_pp = (int*)alloc((size_t)(NP_ + 1) * 4);
  int* bkt_gg = (int*)alloc((size_t)EGG_ * 4);
  int* bkt_tg = (int*)alloc((size_t)ETG_ * 4);
  int* bkt_gps = (int*)alloc((size_t)EGP_ * 4);
  int* bkt_gpd = (int*)alloc((size_t)EGP_ * 4);
  int* bkt_pp = (int*)alloc((size_t)EPP_ * 4);

  hipMemsetAsync(cntbuf, 0, (size_t)NCNT * 2 * 4, stream);
  CsrPack pk;
  pk.c[0] = {gg_dst, EGG_, NG_, cnt_gg, cur_gg, off_gg, bkt_gg};
  pk.c[1] = {tg_dst, ETG_, NG_, cnt_tg, cur_tg, off_tg, bkt_tg};
  pk.c[2] = {gp_src, EGP_, NG_, cnt_gps, cur_gps, off_gps, bkt_gps};
  pk.c[3] = {gp_dst, EGP_, NP_, cnt_gpd, cur_gpd, off_gpd, bkt_gpd};
  pk.c[4] = {pp_dst, EPP_, NP_, cnt_pp, cur_pp, off_pp, bkt_pp};
  hist_all_k<<<dim3((EGG_ + 255) / 256, 5), dim3(256), 0, stream>>>(pk);
  exscan_all_k<<<dim3(5), dim3(256), 0, stream>>>(pk);
  scatter_all_k<<<dim3((EGG_ + 255) / 256, 5), dim3(256), 0, stream>>>(pk);

  const int RG = B_ * NG_;  // 40000
  const int RP = B_ * NP_;  // 6000
  auto gemm = [&](const float* X, const float* W, const float* bias, float* Y, int R, bool relu) {
    dim3 g((R + 63) / 64), blk(256);
    if (relu)
      gemm128_k<1, 0><<<g, blk, 0, stream>>>(X, W, bias, Y, R);
    else
      gemm128_k<0, 0><<<g, blk, 0, stream>>>(X, W, bias, Y, R);
  };

  // ---- Layer 1: h1 = mlp_gg(gene) + scatter(gg_w * (gene@w_gg)[src]) ----
  gemm(gene, w_gg, nullptr, G2, RG, false);
  gemm(gene, mgg_w1, mgg_b1, G1, RG, true);
  gemm(G1, mgg_w2, mgg_b2, G0, RG, false);
  wagg_k<<<dim3((NG_ + 3) / 4, B_), dim3(256), 0, stream>>>(off_gg, bkt_gg, gg_src, gg_w, G2, G0,
                                                            NG_, NG_);
  // ---- Layer 2: TF->gene attention (fused score+prune+agg) ----
  gemm(G0, tg_q, nullptr, G2, RG, false);       // q_gene
  gemm(G0, tg_k, nullptr, G3, RG, false);       // k_tf
  gemm(G0, tg_v_tf, nullptr, G4, RG, false);    // v_tf
  gemm(G0, tg_v_gene, nullptr, G5, RG, false);  // v_gene -> h2 base
  attn_agg_k<<<dim3((NG_ + 3) / 4, B_), dim3(256), 0, stream>>>(
      off_tg, bkt_tg, tg_src, tg_w, G2, G3, G4, G5, NG_, NG_, 16);
  // ---- Layer 3: gene->pathway attention ----
  gemm(G5, gp_k, nullptr, G2, RG, false);   // k_g
  gemm(G5, gp_v, nullptr, G3, RG, false);   // v_g
  gemm(path, gp_q, nullptr, P0, RP, false); // q_p
  gemm(path, mgp_w1, mgp_b1, P1, RP, true);
  gemm(P1, mgp_w2, mgp_b2, P2, RP, false);  // bar base
  attn_agg_k<<<dim3((NP_ + 3) / 4, B_), dim3(256), 0, stream>>>(
      off_gpd, bkt_gpd, gp_src, gp_w, P0, G2, G3, P2, NP_, NG_, 32);
  // ---- Layer 4: pathway-pathway ----
  gemm(P2, w_pp, nullptr, P0, RP, false);  // Yw
  gemm(P2, mpp_w1, mpp_b1, P1, RP, true);
  gemm(P1, mpp_w2, mpp_b2, out_h3, RP, false);
  wagg_k<<<dim3((NP_ + 3) / 4, B_), dim3(256), 0, stream>>>(off_pp, bkt_pp, pp_src, pp_w, P0,
                                                            out_h3, NP_, NP_);
  // ---- Layer 5: pathway->gene feedback ----
  gemm(out_h3, w_pg, nullptr, P0, RP, false);  // Zw
  gemm(G5, mpg_w1, mpg_b1, G1, RG, true);
  gemm(G1, mpg_w2, mpg_b2, out_final, RG, false);
  wagg_k<<<dim3((NG_ + 3) / 4, B_), dim3(256), 0, stream>>>(off_gps, bkt_gps, gp_dst, gp_w, P0,
                                                            out_final, NG_, NP_);
  (void)in_sizes; (void)n_in; (void)out_size; (void)ws_size;
}